// Round 12
// baseline (58.845 us; speedup 1.0000x reference)
//
#include <hip/hip_runtime.h>
#include <cstdint>
#include <cstddef>

#define NPT 128
#define CC 1280
#define MID 128
#define NSPLIT 10

typedef __attribute__((ext_vector_type(8))) short bf16x8;
typedef __attribute__((ext_vector_type(4))) float f32x4;

__device__ __forceinline__ unsigned short f2bf(float f) {
  unsigned u = __builtin_bit_cast(unsigned, f);
  u += 0x7FFFu + ((u >> 16) & 1u);  // RNE
  return (unsigned short)(u >> 16);
}

struct KArgs {
  const float *w2_0, *w2_1, *w2_2, *w2_3;
  unsigned short *W2T0, *W2T1, *W2T2, *W2T3;
  const float* kp;
  const int* subsets;
  int* counts;
  int* plist;
  float* lossm;
  const float* pe;
  const float* w1s;
  const float* b1s;
  float* part;
  const float *b20, *b21, *b22, *b23;
  float *out0, *out1, *out2, *out3;
};

// ===========================================================================
// K1 unit 0..319: pe1 MFMA split-K=10: pe(256x1280)@w1s(1280x512) -> part[10][256][512]
__device__ __forceinline__ void pe1_unit(const KArgs& a, int unit, int tid, char* smem) {
  unsigned short* Asl = (unsigned short*)smem;          // [64 pe-rows][64 k]
  unsigned short* Bsl = (unsigned short*)(smem + 8192); // [64 out-cols][64 k]
  int nt = unit & 7, mt = (unit >> 3) & 3, kz = unit >> 5;  // kz in [0,10)
  int n0 = nt * 64, m0 = mt * 64;
  int l = n0 >> 7, m0c = n0 & 127;
  const float* wbase = a.w1s + (size_t)l * CC * MID + m0c;
  int lane = tid & 63;
  int wave = tid >> 6;
  int lr = lane & 15, lk = lane >> 4;
  int choff = (wave & 1) * 32, spoff = (wave >> 1) * 32;
  f32x4 acc00 = {0.f, 0.f, 0.f, 0.f}, acc01 = acc00, acc10 = acc00, acc11 = acc00;
  for (int sub = 0; sub < 2; ++sub) {
    int kc0 = kz * 128 + sub * 64;
    __syncthreads();
    for (int u = tid; u < 512; u += 256) {
      int r = u >> 3, g = u & 7;
      const float* src = a.pe + (size_t)(m0 + r) * CC + kc0 + g * 8;
      float4 v0 = *reinterpret_cast<const float4*>(src);
      float4 v1 = *reinterpret_cast<const float4*>(src + 4);
      uint4 pk;
      pk.x = (unsigned)f2bf(v0.x) | ((unsigned)f2bf(v0.y) << 16);
      pk.y = (unsigned)f2bf(v0.z) | ((unsigned)f2bf(v0.w) << 16);
      pk.z = (unsigned)f2bf(v1.x) | ((unsigned)f2bf(v1.y) << 16);
      pk.w = (unsigned)f2bf(v1.z) | ((unsigned)f2bf(v1.w) << 16);
      *reinterpret_cast<uint4*>(&Asl[r * 64 + ((g ^ (r & 7)) << 3)]) = pk;
    }
    for (int u = tid; u < 512; u += 256) {
      int r = u & 63, gg = u >> 6;
      float vv[8];
#pragma unroll
      for (int j = 0; j < 8; ++j)
        vv[j] = wbase[(size_t)(kc0 + gg * 8 + j) * MID + r];
      uint4 pk;
      pk.x = (unsigned)f2bf(vv[0]) | ((unsigned)f2bf(vv[1]) << 16);
      pk.y = (unsigned)f2bf(vv[2]) | ((unsigned)f2bf(vv[3]) << 16);
      pk.z = (unsigned)f2bf(vv[4]) | ((unsigned)f2bf(vv[5]) << 16);
      pk.w = (unsigned)f2bf(vv[6]) | ((unsigned)f2bf(vv[7]) << 16);
      *reinterpret_cast<uint4*>(&Bsl[r * 64 + ((gg ^ (r & 7)) << 3)]) = pk;
    }
    __syncthreads();
#pragma unroll
    for (int kk = 0; kk < 64; kk += 32) {
      int gbase = (kk >> 3) + lk;
      int r0w = choff + lr, r1w = choff + 16 + lr;
      int r0a = spoff + lr, r1a = spoff + 16 + lr;
      bf16x8 wf0 = *reinterpret_cast<const bf16x8*>(&Bsl[r0w * 64 + ((gbase ^ (r0w & 7)) << 3)]);
      bf16x8 wf1 = *reinterpret_cast<const bf16x8*>(&Bsl[r1w * 64 + ((gbase ^ (r1w & 7)) << 3)]);
      bf16x8 af0 = *reinterpret_cast<const bf16x8*>(&Asl[r0a * 64 + ((gbase ^ (r0a & 7)) << 3)]);
      bf16x8 af1 = *reinterpret_cast<const bf16x8*>(&Asl[r1a * 64 + ((gbase ^ (r1a & 7)) << 3)]);
      acc00 = __builtin_amdgcn_mfma_f32_16x16x32_bf16(wf0, af0, acc00, 0, 0, 0);
      acc01 = __builtin_amdgcn_mfma_f32_16x16x32_bf16(wf0, af1, acc01, 0, 0, 0);
      acc10 = __builtin_amdgcn_mfma_f32_16x16x32_bf16(wf1, af0, acc10, 0, 0, 0);
      acc11 = __builtin_amdgcn_mfma_f32_16x16x32_bf16(wf1, af1, acc11, 0, 0, 0);
    }
  }
  float* pb = a.part + (size_t)kz * 131072;
#define PEPI(ACC, CI, SI)                                                      \
  {                                                                            \
    int spl = spoff + (SI) * 16 + lr;                                          \
    int chl = choff + (CI) * 16 + lk * 4;                                      \
    float4 v = make_float4(ACC[0], ACC[1], ACC[2], ACC[3]);                    \
    *reinterpret_cast<float4*>(&pb[(size_t)(m0 + spl) * 512 + n0 + chl]) = v;  \
  }
  PEPI(acc00, 0, 0)
  PEPI(acc01, 0, 1)
  PEPI(acc10, 1, 0)
  PEPI(acc11, 1, 1)
#undef PEPI
}

// ===========================================================================
// K1 cheap units c in [0,600): 0-31 binning, 32-471 w2 transpose, 472-599 ones
__device__ __forceinline__ void cheap_unit(const KArgs& a, int c, int tid, char* smem) {
  if (c < 32) {
    int bf = c;
    int* lcnt = (int*)smem;
    for (int i = tid; i < 1024; i += 256) lcnt[i] = 0;
    __syncthreads();
    if (tid < NPT) {
      int p = bf * NPT + tid;
      float kx = a.kp[2 * p], ky = a.kp[2 * p + 1];
      int sub = a.subsets[p];
      if (fminf(kx, ky) >= 0.f && sub != -1) {
        int px = (int)floorf(kx * 32.f);
        px = px < 0 ? 0 : (px > 31 ? 31 : px);
        int py = (int)floorf(ky * 32.f);
        py = py < 0 ? 0 : (py > 31 ? 31 : py);
        int cell = py * 32 + px;
        int slot = atomicAdd(&lcnt[cell], 1);
        if (slot < 32) a.plist[((size_t)bf * 1024 + cell) * 32 + slot] = tid;
      }
    }
    __syncthreads();
    for (int i = tid; i < 1024; i += 256) a.counts[bf * 1024 + i] = lcnt[i];
  } else if (c < 472) {
    float (*ts)[33] = (float(*)[33])smem;
    int local = c - 32;
    const float* w2;
    unsigned short* wt;
    int ch;
    if (local < 40) { w2 = a.w2_0; wt = a.W2T0; ch = 320; }
    else if (local < 120) { w2 = a.w2_1; wt = a.W2T1; ch = 640; local -= 40; }
    else if (local < 280) { w2 = a.w2_2; wt = a.W2T2; ch = 1280; local -= 120; }
    else { w2 = a.w2_3; wt = a.W2T3; ch = 1280; local -= 280; }
    int ctiles = ch >> 5;
    int mt = local / ctiles, ct = local % ctiles;
    int m0 = mt * 32, c0 = ct * 32;
    int i = tid >> 5, j = tid & 31;
#pragma unroll
    for (int r = 0; r < 4; ++r) {
      int m = r * 8 + i;
      ts[m][j] = w2[(size_t)(m0 + m) * ch + c0 + j];
    }
    __syncthreads();
#pragma unroll
    for (int r = 0; r < 4; ++r) {
      int cc = r * 8 + i;
      wt[(size_t)(c0 + cc) * 128 + m0 + j] = f2bf(ts[j][cc]);
    }
  } else {
    int idx = (c - 472) * 256 + tid;
    *reinterpret_cast<float4*>(a.lossm + (size_t)idx * 4) = make_float4(1.f, 1.f, 1.f, 1.f);
  }
}

// ===========================================================================
// K2 body: fused hid + MFMA GEMM, 64sp x 64ch tile x 5 ch-iterations.
// A-staging gathers 10 part slices per cell, applies mean+b1+silu (f32), packs bf16.
// D = mfma(wf, af): lane&15 -> spatial (coalesced scalar stores), reg -> channel.
template <int LOGW, int SCALE, int OFF, bool GATED>
__device__ __forceinline__ void mgemm_body(int bx, int byg, int lvl,
                                           const float* __restrict__ part,
                                           const int* __restrict__ counts,
                                           const int* __restrict__ plist,
                                           const float* __restrict__ b1s,
                                           const unsigned short* __restrict__ W2,
                                           const float* __restrict__ b2,
                                           float* __restrict__ out, int ch,
                                           unsigned short* Asl, unsigned short* Wsl,
                                           float* Ssl, float* Mnl) {
  const int W = 1 << LOGW;
  const int SDIM = 1 << (2 * LOGW);
  int r0 = bx * 64;
  int img = r0 >> (2 * LOGW);
  int tid = threadIdx.x;

  // ---- A staging with fused hid: 1024 (row, granule) units over 4 rounds
  for (int idx = tid; idx < 1024; idx += 256) {
    int r = idx >> 4, g = idx & 15;
    int cr = r0 + r;
    const float* b1p = b1s + lvl * 128 + g * 8;
    float b1v[8];
#pragma unroll
    for (int j = 0; j < 8; ++j) b1v[j] = b1p[j];
    int c00;
    if (GATED) {
      c00 = cr;
    } else {
      int sp = cr & (SDIM - 1);
      int y = sp >> LOGW, x = sp & (W - 1);
      c00 = (cr >> (2 * LOGW)) * 1024 + (SCALE * y + OFF) * 32 + (SCALE * x + OFF);
    }
    float a8[8] = {};
#pragma unroll
    for (int cc = 0; cc < (GATED ? 1 : 4); ++cc) {
      int cell = c00 + (cc & 1) + (cc >> 1) * 32;
      int cnt = counts[cell];
      if (cnt > 0) {
        int cu = cnt < 32 ? cnt : 32;
        int bat = cell >> 14;
        float c8[8] = {};
        for (int i = 0; i < cu; ++i) {
          int p = plist[(size_t)cell * 32 + i];
          const float* rp = part + (size_t)(bat * NPT + p) * 512 + lvl * 128 + g * 8;
#pragma unroll
          for (int z = 0; z < NSPLIT; ++z) {
            float4 v0 = *reinterpret_cast<const float4*>(rp + z * 131072);
            float4 v1 = *reinterpret_cast<const float4*>(rp + z * 131072 + 4);
            c8[0] += v0.x; c8[1] += v0.y; c8[2] += v0.z; c8[3] += v0.w;
            c8[4] += v1.x; c8[5] += v1.y; c8[6] += v1.z; c8[7] += v1.w;
          }
        }
        float invc = 1.f / (float)cnt;
#pragma unroll
        for (int j = 0; j < 8; ++j) {
          float t = c8[j] * invc + b1v[j];
          a8[j] += t / (1.f + expf(-t));
        }
      }
    }
    const float sc = GATED ? 1.f : 0.25f;
    unsigned short pk[8];
#pragma unroll
    for (int j = 0; j < 8; ++j) pk[j] = f2bf(sc * a8[j]);
    uint4 v;
    v.x = (unsigned)pk[0] | ((unsigned)pk[1] << 16);
    v.y = (unsigned)pk[2] | ((unsigned)pk[3] << 16);
    v.z = (unsigned)pk[4] | ((unsigned)pk[5] << 16);
    v.w = (unsigned)pk[6] | ((unsigned)pk[7] << 16);
    *reinterpret_cast<uint4*>(&Asl[r * 128 + ((g ^ (r & 7)) << 3)]) = v;
  }
  // ---- per-row mask terms
  if (tid < 64) {
    int cr = r0 + tid;
    if (GATED) {
      float mv = counts[cr] > 0 ? 1.f : 0.f;
      Ssl[tid] = mv;
      Mnl[tid] = mv;
    } else {
      int sp = cr & (SDIM - 1);
      int y = sp >> LOGW, x = sp & (W - 1);
      int ib = (cr >> (2 * LOGW)) * 1024;
      int c00 = ib + (SCALE * y + OFF) * 32 + (SCALE * x + OFF);
      float sm = (counts[c00] > 0 ? 1.f : 0.f) + (counts[c00 + 1] > 0 ? 1.f : 0.f) +
                 (counts[c00 + 32] > 0 ? 1.f : 0.f) + (counts[c00 + 33] > 0 ? 1.f : 0.f);
      Ssl[tid] = 0.25f * sm;
      Mnl[tid] = counts[ib + (SCALE * y) * 32 + SCALE * x] > 0 ? 1.f : 0.f;
    }
  }
  int lane = tid & 63;
  int wave = tid >> 6;
  int lr = lane & 15, lk = lane >> 4;
  int choff = (wave & 1) * 32, spoff = (wave >> 1) * 32;

  for (int it = 0; it < 5; ++it) {
    int k0 = (byg * 5 + it) * 64;
    __syncthreads();
    for (int idx = tid; idx < 1024; idx += 256) {
      int r = idx >> 4, g = idx & 15;
      uint4 v = *reinterpret_cast<const uint4*>(W2 + (size_t)(k0 + r) * 128 + g * 8);
      *reinterpret_cast<uint4*>(&Wsl[r * 128 + ((g ^ (r & 7)) << 3)]) = v;
    }
    __syncthreads();
    f32x4 a00 = {0.f, 0.f, 0.f, 0.f}, a01 = a00, a10 = a00, a11 = a00;
#pragma unroll
    for (int kk = 0; kk < 128; kk += 32) {
      int gbase = (kk >> 3) + lk;
      int r0w = choff + lr, r1w = choff + 16 + lr;
      int r0a = spoff + lr, r1a = spoff + 16 + lr;
      bf16x8 wf0 = *reinterpret_cast<const bf16x8*>(&Wsl[r0w * 128 + ((gbase ^ (r0w & 7)) << 3)]);
      bf16x8 wf1 = *reinterpret_cast<const bf16x8*>(&Wsl[r1w * 128 + ((gbase ^ (r1w & 7)) << 3)]);
      bf16x8 af0 = *reinterpret_cast<const bf16x8*>(&Asl[r0a * 128 + ((gbase ^ (r0a & 7)) << 3)]);
      bf16x8 af1 = *reinterpret_cast<const bf16x8*>(&Asl[r1a * 128 + ((gbase ^ (r1a & 7)) << 3)]);
      a00 = __builtin_amdgcn_mfma_f32_16x16x32_bf16(wf0, af0, a00, 0, 0, 0);
      a01 = __builtin_amdgcn_mfma_f32_16x16x32_bf16(wf0, af1, a01, 0, 0, 0);
      a10 = __builtin_amdgcn_mfma_f32_16x16x32_bf16(wf1, af0, a10, 0, 0, 0);
      a11 = __builtin_amdgcn_mfma_f32_16x16x32_bf16(wf1, af1, a11, 0, 0, 0);
    }
#define EPI(ACC, CI, SI)                                                          \
    {                                                                             \
      int spl = spoff + (SI) * 16 + lr;                                           \
      int absrow = r0 + spl;                                                      \
      float ss = Ssl[spl], mn = Mnl[spl];                                         \
      float* op = out + (size_t)img * ch * SDIM + (absrow & (SDIM - 1));          \
      _Pragma("unroll")                                                           \
      for (int rr = 0; rr < 4; ++rr) {                                            \
        int chl = k0 + choff + (CI) * 16 + lk * 4 + rr;                           \
        op[(size_t)chl * SDIM] = mn * (ACC[rr] + ss * b2[chl]);                   \
      }                                                                           \
    }
    EPI(a00, 0, 0)
    EPI(a01, 0, 1)
    EPI(a10, 1, 0)
    EPI(a11, 1, 1)
#undef EPI
  }
}

__device__ __forceinline__ void mgemm_unit(const KArgs& a, int unit, char* smem) {
  unsigned short* Asl = (unsigned short*)smem;
  unsigned short* Wsl = (unsigned short*)(smem + 16384);
  float* Ssl = (float*)(smem + 32768);
  float* Mnl = (float*)(smem + 33024);
  if (unit < 512) {
    mgemm_body<5, 1, 0, true>(unit, 0, 0, a.part, a.counts, a.plist, a.b1s,
                              a.W2T0, a.b20, a.out0, 320, Asl, Wsl, Ssl, Mnl);
  } else if (unit < 768) {
    int l = unit - 512;
    mgemm_body<4, 2, 0, false>(l & 127, l >> 7, 1, a.part, a.counts, a.plist, a.b1s,
                               a.W2T1, a.b21, a.out1, 640, Asl, Wsl, Ssl, Mnl);
  } else if (unit < 896) {
    int l = unit - 768;
    mgemm_body<3, 4, 1, false>(l & 31, l >> 5, 2, a.part, a.counts, a.plist, a.b1s,
                               a.W2T2, a.b22, a.out2, 1280, Asl, Wsl, Ssl, Mnl);
  } else {
    int l = unit - 896;
    mgemm_body<3, 4, 1, false>(l & 31, l >> 5, 3, a.part, a.counts, a.plist, a.b1s,
                               a.W2T3, a.b23, a.out3, 1280, Asl, Wsl, Ssl, Mnl);
  }
}

// ===========================================================================
__global__ __launch_bounds__(256) void k_preF(KArgs a) {
  __shared__ __align__(16) char smem[17408];
  int b = blockIdx.x;
  if (b < 320) pe1_unit(a, b, threadIdx.x, smem);
  else cheap_unit(a, b - 320, threadIdx.x, smem);
}
__global__ __launch_bounds__(256) void k_mgemmF(KArgs a) {
  __shared__ __align__(16) char smem[33280];
  mgemm_unit(a, blockIdx.x, smem);
}

// ===========================================================================
extern "C" void kernel_launch(void* const* d_in, const int* in_sizes, int n_in,
                              void* d_out, int out_size, void* d_ws, size_t ws_size,
                              hipStream_t stream) {
  float* out = (float*)d_out;

  float* part = (float*)d_ws;                        // 10*131072 f32
  int* counts = (int*)(part + NSPLIT * 131072);      // 32768
  int* plist = counts + 32768;                       // 32768*32
  unsigned short* W2T0 = (unsigned short*)(plist + 1048576);
  unsigned short* W2T1 = W2T0 + 40960;
  unsigned short* W2T2 = W2T1 + 81920;
  unsigned short* W2T3 = W2T2 + 163840;

  KArgs ka;
  ka.w2_0 = (const float*)d_in[6];
  ka.w2_1 = (const float*)d_in[8];
  ka.w2_2 = (const float*)d_in[10];
  ka.w2_3 = (const float*)d_in[12];
  ka.W2T0 = W2T0; ka.W2T1 = W2T1; ka.W2T2 = W2T2; ka.W2T3 = W2T3;
  ka.kp = (const float*)d_in[1];
  ka.subsets = (const int*)d_in[2];
  ka.counts = counts;
  ka.plist = plist;
  ka.lossm = out + 20971520;
  ka.pe = (const float*)d_in[0];
  ka.w1s = (const float*)d_in[4];
  ka.b1s = (const float*)d_in[5];
  ka.part = part;
  ka.b20 = (const float*)d_in[7];
  ka.b21 = (const float*)d_in[9];
  ka.b22 = (const float*)d_in[11];
  ka.b23 = (const float*)d_in[13];
  ka.out0 = out;
  ka.out1 = out + 10485760;
  ka.out2 = out + 15728640;
  ka.out3 = out + 18350080;

  k_preF<<<dim3(920), dim3(256), 0, stream>>>(ka);
  k_mgemmF<<<dim3(1024), dim3(256), 0, stream>>>(ka);
}

// Round 13
// 41.279 us; speedup vs baseline: 1.4255x; 1.4255x over previous
//
#include <hip/hip_runtime.h>
#include <cstdint>
#include <cstddef>

#define NPT 128
#define CC 1280
#define MID 128
#define NSPLIT 10

typedef __attribute__((ext_vector_type(8))) short bf16x8;
typedef __attribute__((ext_vector_type(4))) float f32x4;

__device__ __forceinline__ unsigned short f2bf(float f) {
  unsigned u = __builtin_bit_cast(unsigned, f);
  u += 0x7FFFu + ((u >> 16) & 1u);  // RNE
  return (unsigned short)(u >> 16);
}

struct KArgs {
  const float *w2_0, *w2_1, *w2_2, *w2_3;
  unsigned short *W2T0, *W2T1, *W2T2, *W2T3;
  const float* kp;
  const int* subsets;
  int* counts;
  int* plist;
  float* lossm;
  const float* pe;
  const float* w1s;
  const float* b1s;
  float* part;
  float* pe1r;
  const float *b20, *b21, *b22, *b23;
  float *out0, *out1, *out2, *out3;
};

// ===========================================================================
// K1 unit 0..319: pe1 MFMA split-K=10: pe(256x1280)@w1s(1280x512) -> part[10][256][512]
__device__ __forceinline__ void pe1_unit(const KArgs& a, int unit, int tid, char* smem) {
  unsigned short* Asl = (unsigned short*)smem;          // [64 pe-rows][64 k]
  unsigned short* Bsl = (unsigned short*)(smem + 8192); // [64 out-cols][64 k]
  int nt = unit & 7, mt = (unit >> 3) & 3, kz = unit >> 5;  // kz in [0,10)
  int n0 = nt * 64, m0 = mt * 64;
  int l = n0 >> 7, m0c = n0 & 127;
  const float* wbase = a.w1s + (size_t)l * CC * MID + m0c;
  int lane = tid & 63;
  int wave = tid >> 6;
  int lr = lane & 15, lk = lane >> 4;
  int choff = (wave & 1) * 32, spoff = (wave >> 1) * 32;
  f32x4 acc00 = {0.f, 0.f, 0.f, 0.f}, acc01 = acc00, acc10 = acc00, acc11 = acc00;
  for (int sub = 0; sub < 2; ++sub) {
    int kc0 = kz * 128 + sub * 64;
    __syncthreads();
    for (int u = tid; u < 512; u += 256) {
      int r = u >> 3, g = u & 7;
      const float* src = a.pe + (size_t)(m0 + r) * CC + kc0 + g * 8;
      float4 v0 = *reinterpret_cast<const float4*>(src);
      float4 v1 = *reinterpret_cast<const float4*>(src + 4);
      uint4 pk;
      pk.x = (unsigned)f2bf(v0.x) | ((unsigned)f2bf(v0.y) << 16);
      pk.y = (unsigned)f2bf(v0.z) | ((unsigned)f2bf(v0.w) << 16);
      pk.z = (unsigned)f2bf(v1.x) | ((unsigned)f2bf(v1.y) << 16);
      pk.w = (unsigned)f2bf(v1.z) | ((unsigned)f2bf(v1.w) << 16);
      *reinterpret_cast<uint4*>(&Asl[r * 64 + ((g ^ (r & 7)) << 3)]) = pk;
    }
    for (int u = tid; u < 512; u += 256) {
      int r = u & 63, gg = u >> 6;
      float vv[8];
#pragma unroll
      for (int j = 0; j < 8; ++j)
        vv[j] = wbase[(size_t)(kc0 + gg * 8 + j) * MID + r];
      uint4 pk;
      pk.x = (unsigned)f2bf(vv[0]) | ((unsigned)f2bf(vv[1]) << 16);
      pk.y = (unsigned)f2bf(vv[2]) | ((unsigned)f2bf(vv[3]) << 16);
      pk.z = (unsigned)f2bf(vv[4]) | ((unsigned)f2bf(vv[5]) << 16);
      pk.w = (unsigned)f2bf(vv[6]) | ((unsigned)f2bf(vv[7]) << 16);
      *reinterpret_cast<uint4*>(&Bsl[r * 64 + ((gg ^ (r & 7)) << 3)]) = pk;
    }
    __syncthreads();
#pragma unroll
    for (int kk = 0; kk < 64; kk += 32) {
      int gbase = (kk >> 3) + lk;
      int r0w = choff + lr, r1w = choff + 16 + lr;
      int r0a = spoff + lr, r1a = spoff + 16 + lr;
      bf16x8 wf0 = *reinterpret_cast<const bf16x8*>(&Bsl[r0w * 64 + ((gbase ^ (r0w & 7)) << 3)]);
      bf16x8 wf1 = *reinterpret_cast<const bf16x8*>(&Bsl[r1w * 64 + ((gbase ^ (r1w & 7)) << 3)]);
      bf16x8 af0 = *reinterpret_cast<const bf16x8*>(&Asl[r0a * 64 + ((gbase ^ (r0a & 7)) << 3)]);
      bf16x8 af1 = *reinterpret_cast<const bf16x8*>(&Asl[r1a * 64 + ((gbase ^ (r1a & 7)) << 3)]);
      acc00 = __builtin_amdgcn_mfma_f32_16x16x32_bf16(wf0, af0, acc00, 0, 0, 0);
      acc01 = __builtin_amdgcn_mfma_f32_16x16x32_bf16(wf0, af1, acc01, 0, 0, 0);
      acc10 = __builtin_amdgcn_mfma_f32_16x16x32_bf16(wf1, af0, acc10, 0, 0, 0);
      acc11 = __builtin_amdgcn_mfma_f32_16x16x32_bf16(wf1, af1, acc11, 0, 0, 0);
    }
  }
  float* pb = a.part + (size_t)kz * 131072;
#define PEPI(ACC, CI, SI)                                                      \
  {                                                                            \
    int spl = spoff + (SI) * 16 + lr;                                          \
    int chl = choff + (CI) * 16 + lk * 4;                                      \
    float4 v = make_float4(ACC[0], ACC[1], ACC[2], ACC[3]);                    \
    *reinterpret_cast<float4*>(&pb[(size_t)(m0 + spl) * 512 + n0 + chl]) = v;  \
  }
  PEPI(acc00, 0, 0)
  PEPI(acc01, 0, 1)
  PEPI(acc10, 1, 0)
  PEPI(acc11, 1, 1)
#undef PEPI
}

// ===========================================================================
// K1 cheap units c in [0,600): 0-31 binning, 32-471 w2 transpose, 472-599 ones
__device__ __forceinline__ void cheap_unit(const KArgs& a, int c, int tid, char* smem) {
  if (c < 32) {
    int bf = c;
    int* lcnt = (int*)smem;
    for (int i = tid; i < 1024; i += 256) lcnt[i] = 0;
    __syncthreads();
    if (tid < NPT) {
      int p = bf * NPT + tid;
      float kx = a.kp[2 * p], ky = a.kp[2 * p + 1];
      int sub = a.subsets[p];
      if (fminf(kx, ky) >= 0.f && sub != -1) {
        int px = (int)floorf(kx * 32.f);
        px = px < 0 ? 0 : (px > 31 ? 31 : px);
        int py = (int)floorf(ky * 32.f);
        py = py < 0 ? 0 : (py > 31 ? 31 : py);
        int cell = py * 32 + px;
        int slot = atomicAdd(&lcnt[cell], 1);
        if (slot < 32) a.plist[((size_t)bf * 1024 + cell) * 32 + slot] = tid;
      }
    }
    __syncthreads();
    for (int i = tid; i < 1024; i += 256) a.counts[bf * 1024 + i] = lcnt[i];
  } else if (c < 472) {
    float (*ts)[33] = (float(*)[33])smem;
    int local = c - 32;
    const float* w2;
    unsigned short* wt;
    int ch;
    if (local < 40) { w2 = a.w2_0; wt = a.W2T0; ch = 320; }
    else if (local < 120) { w2 = a.w2_1; wt = a.W2T1; ch = 640; local -= 40; }
    else if (local < 280) { w2 = a.w2_2; wt = a.W2T2; ch = 1280; local -= 120; }
    else { w2 = a.w2_3; wt = a.W2T3; ch = 1280; local -= 280; }
    int ctiles = ch >> 5;
    int mt = local / ctiles, ct = local % ctiles;
    int m0 = mt * 32, c0 = ct * 32;
    int i = tid >> 5, j = tid & 31;
#pragma unroll
    for (int r = 0; r < 4; ++r) {
      int m = r * 8 + i;
      ts[m][j] = w2[(size_t)(m0 + m) * ch + c0 + j];
    }
    __syncthreads();
#pragma unroll
    for (int r = 0; r < 4; ++r) {
      int cc = r * 8 + i;
      wt[(size_t)(c0 + cc) * 128 + m0 + j] = f2bf(ts[j][cc]);
    }
  } else {
    int idx = (c - 472) * 256 + tid;
    *reinterpret_cast<float4*>(a.lossm + (size_t)idx * 4) = make_float4(1.f, 1.f, 1.f, 1.f);
  }
}

// ===========================================================================
// K1b: pe1r = sum of NSPLIT partials (5.2MB L2-resident read, 0.5MB write)
__global__ __launch_bounds__(256) void k_redF(KArgs a) {
  int i = blockIdx.x * 256 + threadIdx.x;  // 0..32767 float4 groups
  float4 s = make_float4(0.f, 0.f, 0.f, 0.f);
#pragma unroll
  for (int z = 0; z < NSPLIT; ++z) {
    float4 v = *reinterpret_cast<const float4*>(&a.part[(size_t)z * 131072 + (size_t)i * 4]);
    s.x += v.x; s.y += v.y; s.z += v.z; s.w += v.w;
  }
  *reinterpret_cast<float4*>(&a.pe1r[(size_t)i * 4]) = s;
}

// ===========================================================================
// K2 body: fused hid + MFMA GEMM, 64sp x 64ch tile x 5 ch-iterations.
// A-staging gathers the single reduced pe1r slice, mean+b1+silu (f32), packs bf16.
// D = mfma(wf, af): lane&15 -> spatial (coalesced scalar stores), reg -> channel.
template <int LOGW, int SCALE, int OFF, bool GATED>
__device__ __forceinline__ void mgemm_body(int bx, int byg, int lvl,
                                           const float* __restrict__ pe1r,
                                           const int* __restrict__ counts,
                                           const int* __restrict__ plist,
                                           const float* __restrict__ b1s,
                                           const unsigned short* __restrict__ W2,
                                           const float* __restrict__ b2,
                                           float* __restrict__ out, int ch,
                                           unsigned short* Asl, unsigned short* Wsl,
                                           float* Ssl, float* Mnl) {
  const int W = 1 << LOGW;
  const int SDIM = 1 << (2 * LOGW);
  int r0 = bx * 64;
  int img = r0 >> (2 * LOGW);
  int tid = threadIdx.x;

  // ---- A staging with fused hid: 1024 (row, granule) units over 4 rounds
  for (int idx = tid; idx < 1024; idx += 256) {
    int r = idx >> 4, g = idx & 15;
    int cr = r0 + r;
    const float* b1p = b1s + lvl * 128 + g * 8;
    float b1v[8];
#pragma unroll
    for (int j = 0; j < 8; ++j) b1v[j] = b1p[j];
    int c00;
    if (GATED) {
      c00 = cr;
    } else {
      int sp = cr & (SDIM - 1);
      int y = sp >> LOGW, x = sp & (W - 1);
      c00 = (cr >> (2 * LOGW)) * 1024 + (SCALE * y + OFF) * 32 + (SCALE * x + OFF);
    }
    float a8[8] = {};
#pragma unroll
    for (int cc = 0; cc < (GATED ? 1 : 4); ++cc) {
      int cell = c00 + (cc & 1) + (cc >> 1) * 32;
      int cnt = counts[cell];
      if (cnt > 0) {
        int cu = cnt < 32 ? cnt : 32;
        int bat = cell >> 14;
        float c8[8] = {};
        for (int i = 0; i < cu; ++i) {
          int p = plist[(size_t)cell * 32 + i];
          const float* rp = pe1r + (size_t)(bat * NPT + p) * 512 + lvl * 128 + g * 8;
          float4 v0 = *reinterpret_cast<const float4*>(rp);
          float4 v1 = *reinterpret_cast<const float4*>(rp + 4);
          c8[0] += v0.x; c8[1] += v0.y; c8[2] += v0.z; c8[3] += v0.w;
          c8[4] += v1.x; c8[5] += v1.y; c8[6] += v1.z; c8[7] += v1.w;
        }
        float invc = 1.f / (float)cnt;
#pragma unroll
        for (int j = 0; j < 8; ++j) {
          float t = c8[j] * invc + b1v[j];
          a8[j] += t / (1.f + expf(-t));
        }
      }
    }
    const float sc = GATED ? 1.f : 0.25f;
    unsigned short pk[8];
#pragma unroll
    for (int j = 0; j < 8; ++j) pk[j] = f2bf(sc * a8[j]);
    uint4 v;
    v.x = (unsigned)pk[0] | ((unsigned)pk[1] << 16);
    v.y = (unsigned)pk[2] | ((unsigned)pk[3] << 16);
    v.z = (unsigned)pk[4] | ((unsigned)pk[5] << 16);
    v.w = (unsigned)pk[6] | ((unsigned)pk[7] << 16);
    *reinterpret_cast<uint4*>(&Asl[r * 128 + ((g ^ (r & 7)) << 3)]) = v;
  }
  // ---- per-row mask terms
  if (tid < 64) {
    int cr = r0 + tid;
    if (GATED) {
      float mv = counts[cr] > 0 ? 1.f : 0.f;
      Ssl[tid] = mv;
      Mnl[tid] = mv;
    } else {
      int sp = cr & (SDIM - 1);
      int y = sp >> LOGW, x = sp & (W - 1);
      int ib = (cr >> (2 * LOGW)) * 1024;
      int c00 = ib + (SCALE * y + OFF) * 32 + (SCALE * x + OFF);
      float sm = (counts[c00] > 0 ? 1.f : 0.f) + (counts[c00 + 1] > 0 ? 1.f : 0.f) +
                 (counts[c00 + 32] > 0 ? 1.f : 0.f) + (counts[c00 + 33] > 0 ? 1.f : 0.f);
      Ssl[tid] = 0.25f * sm;
      Mnl[tid] = counts[ib + (SCALE * y) * 32 + SCALE * x] > 0 ? 1.f : 0.f;
    }
  }
  int lane = tid & 63;
  int wave = tid >> 6;
  int lr = lane & 15, lk = lane >> 4;
  int choff = (wave & 1) * 32, spoff = (wave >> 1) * 32;

  for (int it = 0; it < 5; ++it) {
    int k0 = (byg * 5 + it) * 64;
    __syncthreads();
    for (int idx = tid; idx < 1024; idx += 256) {
      int r = idx >> 4, g = idx & 15;
      uint4 v = *reinterpret_cast<const uint4*>(W2 + (size_t)(k0 + r) * 128 + g * 8);
      *reinterpret_cast<uint4*>(&Wsl[r * 128 + ((g ^ (r & 7)) << 3)]) = v;
    }
    __syncthreads();
    f32x4 a00 = {0.f, 0.f, 0.f, 0.f}, a01 = a00, a10 = a00, a11 = a00;
#pragma unroll
    for (int kk = 0; kk < 128; kk += 32) {
      int gbase = (kk >> 3) + lk;
      int r0w = choff + lr, r1w = choff + 16 + lr;
      int r0a = spoff + lr, r1a = spoff + 16 + lr;
      bf16x8 wf0 = *reinterpret_cast<const bf16x8*>(&Wsl[r0w * 128 + ((gbase ^ (r0w & 7)) << 3)]);
      bf16x8 wf1 = *reinterpret_cast<const bf16x8*>(&Wsl[r1w * 128 + ((gbase ^ (r1w & 7)) << 3)]);
      bf16x8 af0 = *reinterpret_cast<const bf16x8*>(&Asl[r0a * 128 + ((gbase ^ (r0a & 7)) << 3)]);
      bf16x8 af1 = *reinterpret_cast<const bf16x8*>(&Asl[r1a * 128 + ((gbase ^ (r1a & 7)) << 3)]);
      a00 = __builtin_amdgcn_mfma_f32_16x16x32_bf16(wf0, af0, a00, 0, 0, 0);
      a01 = __builtin_amdgcn_mfma_f32_16x16x32_bf16(wf0, af1, a01, 0, 0, 0);
      a10 = __builtin_amdgcn_mfma_f32_16x16x32_bf16(wf1, af0, a10, 0, 0, 0);
      a11 = __builtin_amdgcn_mfma_f32_16x16x32_bf16(wf1, af1, a11, 0, 0, 0);
    }
#define EPI(ACC, CI, SI)                                                          \
    {                                                                             \
      int spl = spoff + (SI) * 16 + lr;                                           \
      int absrow = r0 + spl;                                                      \
      float ss = Ssl[spl], mn = Mnl[spl];                                         \
      float* op = out + (size_t)img * ch * SDIM + (absrow & (SDIM - 1));          \
      _Pragma("unroll")                                                           \
      for (int rr = 0; rr < 4; ++rr) {                                            \
        int chl = k0 + choff + (CI) * 16 + lk * 4 + rr;                           \
        op[(size_t)chl * SDIM] = mn * (ACC[rr] + ss * b2[chl]);                   \
      }                                                                           \
    }
    EPI(a00, 0, 0)
    EPI(a01, 0, 1)
    EPI(a10, 1, 0)
    EPI(a11, 1, 1)
#undef EPI
  }
}

__device__ __forceinline__ void mgemm_unit(const KArgs& a, int unit, char* smem) {
  unsigned short* Asl = (unsigned short*)smem;
  unsigned short* Wsl = (unsigned short*)(smem + 16384);
  float* Ssl = (float*)(smem + 32768);
  float* Mnl = (float*)(smem + 33024);
  if (unit < 512) {
    mgemm_body<5, 1, 0, true>(unit, 0, 0, a.pe1r, a.counts, a.plist, a.b1s,
                              a.W2T0, a.b20, a.out0, 320, Asl, Wsl, Ssl, Mnl);
  } else if (unit < 768) {
    int l = unit - 512;
    mgemm_body<4, 2, 0, false>(l & 127, l >> 7, 1, a.pe1r, a.counts, a.plist, a.b1s,
                               a.W2T1, a.b21, a.out1, 640, Asl, Wsl, Ssl, Mnl);
  } else if (unit < 896) {
    int l = unit - 768;
    mgemm_body<3, 4, 1, false>(l & 31, l >> 5, 2, a.pe1r, a.counts, a.plist, a.b1s,
                               a.W2T2, a.b22, a.out2, 1280, Asl, Wsl, Ssl, Mnl);
  } else {
    int l = unit - 896;
    mgemm_body<3, 4, 1, false>(l & 31, l >> 5, 3, a.pe1r, a.counts, a.plist, a.b1s,
                               a.W2T3, a.b23, a.out3, 1280, Asl, Wsl, Ssl, Mnl);
  }
}

// ===========================================================================
__global__ __launch_bounds__(256) void k_preF(KArgs a) {
  __shared__ __align__(16) char smem[17408];
  int b = blockIdx.x;
  if (b < 320) pe1_unit(a, b, threadIdx.x, smem);
  else cheap_unit(a, b - 320, threadIdx.x, smem);
}
__global__ __launch_bounds__(256) void k_mgemmF(KArgs a) {
  __shared__ __align__(16) char smem[33280];
  mgemm_unit(a, blockIdx.x, smem);
}

// ===========================================================================
extern "C" void kernel_launch(void* const* d_in, const int* in_sizes, int n_in,
                              void* d_out, int out_size, void* d_ws, size_t ws_size,
                              hipStream_t stream) {
  float* out = (float*)d_out;

  float* part = (float*)d_ws;                        // NSPLIT*131072 f32
  float* pe1r = part + NSPLIT * 131072;              // 131072 f32
  int* counts = (int*)(pe1r + 131072);               // 32768
  int* plist = counts + 32768;                       // 32768*32
  unsigned short* W2T0 = (unsigned short*)(plist + 1048576);
  unsigned short* W2T1 = W2T0 + 40960;
  unsigned short* W2T2 = W2T1 + 81920;
  unsigned short* W2T3 = W2T2 + 163840;

  KArgs ka;
  ka.w2_0 = (const float*)d_in[6];
  ka.w2_1 = (const float*)d_in[8];
  ka.w2_2 = (const float*)d_in[10];
  ka.w2_3 = (const float*)d_in[12];
  ka.W2T0 = W2T0; ka.W2T1 = W2T1; ka.W2T2 = W2T2; ka.W2T3 = W2T3;
  ka.kp = (const float*)d_in[1];
  ka.subsets = (const int*)d_in[2];
  ka.counts = counts;
  ka.plist = plist;
  ka.lossm = out + 20971520;
  ka.pe = (const float*)d_in[0];
  ka.w1s = (const float*)d_in[4];
  ka.b1s = (const float*)d_in[5];
  ka.part = part;
  ka.pe1r = pe1r;
  ka.b20 = (const float*)d_in[7];
  ka.b21 = (const float*)d_in[9];
  ka.b22 = (const float*)d_in[11];
  ka.b23 = (const float*)d_in[13];
  ka.out0 = out;
  ka.out1 = out + 10485760;
  ka.out2 = out + 15728640;
  ka.out3 = out + 18350080;

  k_preF<<<dim3(920), dim3(256), 0, stream>>>(ka);
  k_redF<<<dim3(128), dim3(256), 0, stream>>>(ka);
  k_mgemmF<<<dim3(1024), dim3(256), 0, stream>>>(ka);
}